// Round 10
// baseline (464.273 us; speedup 1.0000x reference)
//
#include <hip/hip_runtime.h>
#include <hip/hip_bf16.h>
#include <stdint.h>

#define BATCH  8192
#define NFEAT  8192
#define DMODEL 1024

typedef unsigned short u16;
typedef __attribute__((ext_vector_type(8))) short  short8;
typedef __attribute__((ext_vector_type(4))) float  f32x4;

// fp32 -> bf16 round-to-nearest-even
__device__ __forceinline__ u16 f2b(float f) {
    uint32_t u = __float_as_uint(f);
    u += 0x7fffu + ((u >> 16) & 1u);
    return (u16)(u >> 16);
}

// async global->LDS, 16B per lane; LDS dest is wave-uniform base + lane*16 (HW rule)
__device__ __forceinline__ void gld16(const u16* g, void* l) {
    __builtin_amdgcn_global_load_lds(
        (const __attribute__((address_space(1))) void*)(uintptr_t)g,
        (__attribute__((address_space(3))) void*)(uint32_t)(uintptr_t)l,
        16, 0, 0);
}

// ---------------- conversion kernel (W only; x conversion fused into gemm1) ----------------

__global__ void cvt_w_kernel(const float* __restrict__ W,
                             u16* __restrict__ wb, u16* __restrict__ wt) {
    __shared__ u16 tile[64][65];
    const int f0 = blockIdx.x * 64;
    const int d0 = blockIdx.y * 64;
    const int t  = threadIdx.x;
#pragma unroll
    for (int rep = 0; rep < 16; ++rep) {
        int idx = rep * 256 + t;
        int r = idx >> 6, c = idx & 63;
        float v = W[(size_t)(f0 + r) * DMODEL + d0 + c];
        u16 u = f2b(v);
        tile[r][c] = u;
        wb[(size_t)(f0 + r) * DMODEL + d0 + c] = u;
    }
    __syncthreads();
#pragma unroll
    for (int rep = 0; rep < 16; ++rep) {
        int idx = rep * 256 + t;
        int r = idx >> 6, c = idx & 63;
        wt[(size_t)(d0 + r) * NFEAT + f0 + c] = tile[c][r];
    }
}

#define SYNC_IN()  do { __builtin_amdgcn_s_barrier(); \
                        asm volatile("s_waitcnt lgkmcnt(0)" ::: "memory"); } while (0)
#define SYNC_OUT() do { __builtin_amdgcn_s_setprio(0); __builtin_amdgcn_s_barrier(); } while (0)

// ---------------- GEMM 1 (fused x-cvt): H = bf16(X) @ B^T, 256x128 tile, 8-phase ----------
// X [M][K] fp32, B [N][K] bf16, H [M][N] bf16. Grid = (M/256)*(N/128) = 256 blocks.
// A-path: q0 of tile t issues 8x dwordx4 of X(t+2) into named reg buffer (rbE/rbO);
// q0 of tile t+1 drains it (full 8-barrier tile of latency cover) and converts+writes
// it into LDS INSIDE the setprio MFMA region (cvt VALU hidden under 16 MFMA).
// LDS 96 KiB: A 2buf x 32 KiB @0, B 2buf x 16 KiB @65536.
__global__ __launch_bounds__(512, 2)
void gemm1_fused(const float* __restrict__ X, const u16* __restrict__ B,
                 u16* __restrict__ H, int N, int K) {
    const int NT = K >> 6;                  // 128
    __shared__ __align__(1024) char lds[98304];
    const int BOFF = 65536;

    const int tid  = threadIdx.x;
    const int lane = tid & 63;
    const int wave = tid >> 6;              // 0..7
    const int wm   = wave >> 2;             // 0..1 (128-row half)
    const int wn   = wave & 3;              // 0..3 (32-col group)

    const int nwg = gridDim.x;
    const int swz = (blockIdx.x & 7) * (nwg >> 3) + (blockIdx.x >> 3);
    const int ntn = N >> 7;                 // 8
    const int tm0 = (swz / ntn) << 8;
    const int tn0 = (swz % ntn) << 7;

    const int srl = lane >> 2;
    const int sch = (lane & 3) ^ (((lane >> 5) & 1) << 1);
    const int scol  = (wave & 1) * 32 + sch * 8;    // element col (pre-swizzled)
    const int srow0 = (wave >> 1) * 16 + srl;

    // fp32 A sources: same rows/cols the bf16 gld16 path used
    const float* px[2][2];
    px[0][0] = X + (size_t)(tm0 + srow0)            * K + scol;
    px[0][1] = X + (size_t)(tm0 + srow0 + 64)       * K + scol;
    px[1][0] = X + (size_t)(tm0 + 128 + srow0)      * K + scol;
    px[1][1] = X + (size_t)(tm0 + 128 + srow0 + 64) * K + scol;
    const u16* pb[2];
    pb[0] = B + (size_t)(tn0 + srow0)      * K + scol;
    pb[1] = B + (size_t)(tn0 + srow0 + 64) * K + scol;

    char* const awr = lds + wave * 1024 + lane * 16;   // A write slot (buf 0)

    f32x4 rbE[8], rbO[8];                   // named double buffers (static idx, rule #20)
    auto LOAD_RAW = [&](int tau, f32x4* rb) {
#pragma unroll
        for (int h = 0; h < 2; ++h)
#pragma unroll
            for (int j = 0; j < 2; ++j)
#pragma unroll
                for (int v = 0; v < 2; ++v)
                    rb[h * 4 + j * 2 + v] =
                        *(const f32x4*)(px[h][j] + (size_t)tau * 64 + v * 4);
    };
    auto WRITE_A = [&](int buf, const f32x4* rb) {     // cvt + 4x ds_write_b128
#pragma unroll
        for (int h = 0; h < 2; ++h)
#pragma unroll
            for (int j = 0; j < 2; ++j) {
                union { u16 u[8]; uint4 v; } o;
#pragma unroll
                for (int v = 0; v < 2; ++v)
#pragma unroll
                    for (int e = 0; e < 4; ++e)
                        o.u[v * 4 + e] = f2b(rb[h * 4 + j * 2 + v][e]);
                *(uint4*)(awr + buf * 32768 + h * 16384 + j * 8192) = o.v;
            }
    };
    auto STAGE_B = [&](int tau, int par) {
        char* d = lds + BOFF + par * 16384 + wave * 1024;
        gld16(pb[0] + (size_t)tau * 64, d);
        gld16(pb[1] + (size_t)tau * 64, d + 8192);
    };

    const int l15 = lane & 15, lhi = lane >> 4;
    const int pch = lhi ^ (((lane >> 3) & 1) << 1);
    const int lof = l15 * 64 + pch * 16;

    short8 a[4][2];
    short8 b[2][2];
    f32x4  acc[8][2] = {};

    auto MMA_ = [&](int mh, int nh) {
#pragma unroll
        for (int ks = 0; ks < 2; ++ks)
#pragma unroll
            for (int fm = 0; fm < 4; ++fm)
                acc[mh * 4 + fm][nh] = __builtin_amdgcn_mfma_f32_16x16x32_bf16(
                    a[fm][ks], b[nh][ks], acc[mh * 4 + fm][nh], 0, 0, 0);
    };

    // one K-step; par = t&1 compile-time at each call site
    auto KSTEP = [&](int t, f32x4* ldst, const f32x4* wsrc, int par) {
        const char* Ab = lds + par * 32768 + wm * 16384 + lof;
        const char* Bb = lds + BOFF + par * 16384 + wn * 4096 + lof;

        // ---- q0: issue raw X(t+2); read A[mh0]+B[nh0]; drain raw(t+1); cvt+write A(t+1)
        if (t + 2 < NT) LOAD_RAW(t + 2, ldst);
#pragma unroll
        for (int fm = 0; fm < 4; ++fm)
#pragma unroll
            for (int ks = 0; ks < 2; ++ks)
                a[fm][ks] = *(const short8*)(Ab + ((0 * 4 + fm) * 2 + ks) * 1024);
#pragma unroll
        for (int ks = 0; ks < 2; ++ks)
            b[0][ks] = *(const short8*)(Bb + (0 * 2 + ks) * 1024);
        // queue: [raw(t+1)8, B(t+1)2, raw(t+2)8] -> drain raw(t+1), keep 10
        if (t + 2 < NT)      asm volatile("s_waitcnt vmcnt(10)" ::: "memory");
        else if (t + 1 < NT) asm volatile("s_waitcnt vmcnt(2)" ::: "memory");
        SYNC_IN();
        __builtin_amdgcn_s_setprio(1);
        if (t + 1 < NT) WRITE_A(par ^ 1, wsrc);   // hidden under MMA below
        MMA_(0, 0);
        SYNC_OUT();

        // ---- q1
#pragma unroll
        for (int ks = 0; ks < 2; ++ks)
            b[1][ks] = *(const short8*)(Bb + (1 * 2 + ks) * 1024);
        SYNC_IN();
        __builtin_amdgcn_s_setprio(1);
        MMA_(0, 1);
        SYNC_OUT();

        // ---- q2: read A[mh1]; stage B(t+2)
#pragma unroll
        for (int fm = 0; fm < 4; ++fm)
#pragma unroll
            for (int ks = 0; ks < 2; ++ks)
                a[fm][ks] = *(const short8*)(Ab + ((1 * 4 + fm) * 2 + ks) * 1024);
        if (t + 2 < NT) STAGE_B(t + 2, par);
        SYNC_IN();
        __builtin_amdgcn_s_setprio(1);
        MMA_(1, 1);
        SYNC_OUT();

        // ---- q3: drain B(t+1) (keep t+2's 10)
        __builtin_amdgcn_s_barrier();
        __builtin_amdgcn_s_setprio(1);
        MMA_(1, 0);
        __builtin_amdgcn_s_setprio(0);
        if (t < NT - 2) asm volatile("s_waitcnt vmcnt(10)" ::: "memory");
        else            asm volatile("s_waitcnt vmcnt(0)"  ::: "memory");
        __builtin_amdgcn_s_barrier();
    };

    // prologue: raw(0), B(0), raw(1), B(1) in flight; drain raw(0)+B(0); write A(0)
    LOAD_RAW(0, rbE);
    STAGE_B(0, 0);
    LOAD_RAW(1, rbO);
    STAGE_B(1, 1);
    asm volatile("s_waitcnt vmcnt(10)" ::: "memory");
    WRITE_A(0, rbE);
    asm volatile("s_waitcnt lgkmcnt(0)" ::: "memory");
    __builtin_amdgcn_s_barrier();

    for (int t = 0; t < NT; t += 2) {
        KSTEP(t,     rbE, rbO, 0);   // even: load raw(t+2)->rbE, write A(t+1) from rbO
        KSTEP(t + 1, rbO, rbE, 1);   // odd : load raw(t+3)->rbO, write A(t+2) from rbE
    }

    // epilogue: bf16 tile via LDS transpose, coalesced 16B stores
    u16* lu = (u16*)lds;
#pragma unroll
    for (int fm = 0; fm < 8; ++fm)
#pragma unroll
        for (int nh = 0; nh < 2; ++nh) {
            const int col  = wn * 32 + nh * 16 + l15;
            const int row0 = wm * 128 + fm * 16 + lhi * 4;
#pragma unroll
            for (int r = 0; r < 4; ++r)
                lu[(row0 + r) * 128 + col] = f2b(acc[fm][nh][r]);
        }
    __syncthreads();
    const uint4* ls = (const uint4*)lds;
#pragma unroll
    for (int s = 0; s < 8; ++s) {
        int i = s * 512 + tid;
        int row = i >> 4;
        int col = (i & 15) * 8;
        *(uint4*)(H + (size_t)(tm0 + row) * N + (tn0 + col)) = ls[i];
    }
}

// ---------------- GEMM 2: PERSISTENT 1024x256 column-panel blocks (round-9, best) ----------
__global__ __launch_bounds__(512, 2)
void gemm2_persist(const u16* __restrict__ A, const u16* __restrict__ B,
                   float* __restrict__ O, const float* __restrict__ bias,
                   int N, int K) {
    __shared__ __align__(1024) char lds[163840];
    const int BOFF = 98304;
    const int TTOT = 64;

    const int tid  = threadIdx.x;
    const int lane = tid & 63;
    const int wave = tid >> 6;
    const int wm   = wave >> 2;
    const int wn   = wave & 3;

    const int bid = blockIdx.x;
    const int xcd = bid & 7;
    const int sub = (bid >> 3) & 3;
    const int mg  = bid >> 5;
    const int tn0     = ((xcd << 2) + sub) << 8;
    const int tm_base = mg << 10;

    const int srl = lane >> 2;
    const int sch = (lane & 3) ^ (((lane >> 5) & 1) << 1);
    const int scol  = (wave & 1) * 32 + sch * 8;
    const int srow0 = (wave >> 1) * 16 + srl;

    auto STAGE_A = [&](int tau, int half) {
        if (tau < TTOT) {
            char* d = lds + (tau % 3) * 32768 + half * 16384 + wave * 1024;
            const int rb = tm_base + ((tau >> 4) << 8) + half * 128 + srow0;
            const u16* p = A + (size_t)rb * K + ((tau & 15) << 6) + scol;
            gld16(p, d);
            gld16(p + (size_t)64 * K, d + 8192);
        }
    };
    auto STAGE_B = [&](int tau, int half) {
        if (tau < TTOT) {
            char* d = lds + BOFF + (tau & 1) * 32768 + half * 16384 + wave * 1024;
            const u16* p = B + (size_t)(tn0 + half * 128 + srow0) * K + ((tau & 15) << 6) + scol;
            gld16(p, d);
            gld16(p + (size_t)64 * K, d + 8192);
        }
    };

    const int l15 = lane & 15, lhi = lane >> 4;
    const int pch = lhi ^ (((lane >> 3) & 1) << 1);
    const int lof = l15 * 64 + pch * 16;

    short8 a[4][2];
    short8 b[4][2];
    f32x4  acc[8][4] = {};

    const char* Ab;
    const char* Bb;
    auto LDA_ = [&](int mh) {
#pragma unroll
        for (int fm = 0; fm < 4; ++fm)
#pragma unroll
            for (int ks = 0; ks < 2; ++ks)
                a[fm][ks] = *(const short8*)(Ab + ((mh * 4 + fm) * 2 + ks) * 1024);
    };
    auto LDB_ = [&](int nh) {
#pragma unroll
        for (int fn = 0; fn < 2; ++fn)
#pragma unroll
            for (int ks = 0; ks < 2; ++ks)
                b[nh * 2 + fn][ks] = *(const short8*)(Bb + (((wn & 1) * 4 + nh * 2 + fn) * 2 + ks) * 1024);
    };
    auto MMA_ = [&](int mh, int nh) {
#pragma unroll
        for (int ks = 0; ks < 2; ++ks)
#pragma unroll
            for (int fm = 0; fm < 4; ++fm)
#pragma unroll
                for (int fn = 0; fn < 2; ++fn)
                    acc[mh * 4 + fm][nh * 2 + fn] = __builtin_amdgcn_mfma_f32_16x16x32_bf16(
                        a[fm][ks], b[nh * 2 + fn][ks], acc[mh * 4 + fm][nh * 2 + fn], 0, 0, 0);
    };

    const int ocol = tn0 + wn * 64;
    float bv[4];
#pragma unroll
    for (int fn = 0; fn < 4; ++fn) bv[fn] = bias[ocol + fn * 16 + l15];

    STAGE_A(0, 0); STAGE_A(0, 1); STAGE_B(0, 0); STAGE_B(0, 1);
    STAGE_A(1, 0); STAGE_A(1, 1); STAGE_B(1, 0); STAGE_B(1, 1);
    asm volatile("s_waitcnt vmcnt(8)" ::: "memory");
    __builtin_amdgcn_s_barrier();

    for (int tt = 0; tt < TTOT; ++tt) {
        Ab = lds + (tt % 3) * 32768 + wm * 16384 + lof;
        Bb = lds + BOFF + (tt & 1) * 32768 + (wn >> 1) * 16384 + lof;

        LDA_(0); LDB_(0);
        STAGE_A(tt + 2, 0);
        asm volatile("s_waitcnt lgkmcnt(8)" ::: "memory");
        SYNC_IN();
        __builtin_amdgcn_s_setprio(1);
        MMA_(0, 0);
        SYNC_OUT();

        LDB_(1);
        STAGE_A(tt + 2, 1);
        SYNC_IN();
        __builtin_amdgcn_s_setprio(1);
        MMA_(0, 1);
        SYNC_OUT();

        LDA_(1);
        STAGE_B(tt + 2, 0);
        SYNC_IN();
        __builtin_amdgcn_s_setprio(1);
        MMA_(1, 1);
        SYNC_OUT();

        STAGE_B(tt + 2, 1);
        __builtin_amdgcn_s_barrier();
        asm volatile("s_waitcnt lgkmcnt(0)" ::: "memory");
        __builtin_amdgcn_s_setprio(1);
        MMA_(1, 0);
        __builtin_amdgcn_s_setprio(0);
        if (tt < TTOT - 2)       asm volatile("s_waitcnt vmcnt(8)" ::: "memory");
        else if (tt == TTOT - 2) asm volatile("s_waitcnt vmcnt(0)" ::: "memory");
        __builtin_amdgcn_s_barrier();

        if ((tt & 15) == 15) {
            const int orow = tm_base + ((tt >> 4) << 8) + wm * 128;
#pragma unroll
            for (int fm = 0; fm < 8; ++fm) {
                const int row0 = orow + fm * 16 + lhi * 4;
#pragma unroll
                for (int fn = 0; fn < 4; ++fn) {
                    const int col = ocol + fn * 16 + l15;
#pragma unroll
                    for (int r = 0; r < 4; ++r) {
                        float v = acc[fm][fn][r] + bv[fn];
                        O[(size_t)(row0 + r) * N + col] = v > 0.f ? v : 0.f;
                        acc[fm][fn][r] = 0.f;
                    }
                }
            }
        }
    }
}

// ---------------- launch ----------------

extern "C" void kernel_launch(void* const* d_in, const int* in_sizes, int n_in,
                              void* d_out, int out_size, void* d_ws, size_t ws_size,
                              hipStream_t stream) {
    const float* x    = (const float*)d_in[0];   // [8192, 8192]
    const float* W    = (const float*)d_in[1];   // [8192, 1024]
    const float* bias = (const float*)d_in[2];   // [8192]
    float* out = (float*)d_out;                  // [8192, 8192] fp32

    char* ws = (char*)d_ws;
    u16* wt = (u16*)ws;                          // [1024][8192]  16 MB
    u16* wb = (u16*)(ws + 16777216);             // [8192][1024]  16 MB
    u16* hb = (u16*)(ws + 2 * 16777216);         // [8192][1024]  16 MB

    cvt_w_kernel<<<dim3(NFEAT / 64, DMODEL / 64), 256, 0, stream>>>(W, wb, wt);

    // h = bf16(x) @ W -> bf16 (x converted in-flight; no cvt_x pass, no xb buffer)
    gemm1_fused<<<dim3((BATCH / 256) * (DMODEL / 128)), 512, 0, stream>>>(
        x, wt, hb, DMODEL, NFEAT);

    // out = relu(h @ W^T + bias)
    gemm2_persist<<<dim3(256), 512, 0, stream>>>(
        hb, wb, out, bias, NFEAT, DMODEL);
}

// Round 11
// 403.486 us; speedup vs baseline: 1.1507x; 1.1507x over previous
//
#include <hip/hip_runtime.h>
#include <hip/hip_bf16.h>
#include <stdint.h>

#define BATCH  8192
#define NFEAT  8192
#define DMODEL 1024

typedef unsigned short u16;
typedef __attribute__((ext_vector_type(8))) short  short8;
typedef __attribute__((ext_vector_type(4))) float  f32x4;

// fp32 -> bf16 round-to-nearest-even (scalar path, conversion kernels)
__device__ __forceinline__ u16 f2b(float f) {
    uint32_t u = __float_as_uint(f);
    u += 0x7fffu + ((u >> 16) & 1u);
    return (u16)(u >> 16);
}

// packed fp32x2 -> bf16x2, RNE (hardware cvt; identical rounding to f2b for finite inputs)
__device__ __forceinline__ uint32_t cvtpk(float a, float b) {
    uint32_t r;
    asm("v_cvt_pk_bf16_f32 %0, %1, %2" : "=v"(r) : "v"(a), "v"(b));
    return r;
}

// async global->LDS, 16B per lane; LDS dest is wave-uniform base + lane*16 (HW rule)
__device__ __forceinline__ void gld16(const u16* g, void* l) {
    __builtin_amdgcn_global_load_lds(
        (const __attribute__((address_space(1))) void*)(uintptr_t)g,
        (__attribute__((address_space(3))) void*)(uint32_t)(uintptr_t)l,
        16, 0, 0);
}

// ---------------- conversion kernel (W only; x conversion fused into gemm1) ----------------

__global__ void cvt_w_kernel(const float* __restrict__ W,
                             u16* __restrict__ wb, u16* __restrict__ wt) {
    __shared__ u16 tile[64][65];
    const int f0 = blockIdx.x * 64;
    const int d0 = blockIdx.y * 64;
    const int t  = threadIdx.x;
#pragma unroll
    for (int rep = 0; rep < 16; ++rep) {
        int idx = rep * 256 + t;
        int r = idx >> 6, c = idx & 63;
        float v = W[(size_t)(f0 + r) * DMODEL + d0 + c];
        u16 u = f2b(v);
        tile[r][c] = u;
        wb[(size_t)(f0 + r) * DMODEL + d0 + c] = u;
    }
    __syncthreads();
#pragma unroll
    for (int rep = 0; rep < 16; ++rep) {
        int idx = rep * 256 + t;
        int r = idx >> 6, c = idx & 63;
        wt[(size_t)(d0 + r) * NFEAT + f0 + c] = tile[c][r];
    }
}

#define SYNC_IN()  do { __builtin_amdgcn_s_barrier(); \
                        asm volatile("s_waitcnt lgkmcnt(0)" ::: "memory"); } while (0)
#define SYNC_OUT() do { __builtin_amdgcn_s_setprio(0); __builtin_amdgcn_s_barrier(); } while (0)

// ---------------- GEMM 1 (fused x-cvt, scratch-proofed): H = bf16(X) @ B^T ----------------
// X [M][K] fp32, B [N][K] bf16, H [M][N] bf16. 256x128 tile, 8 waves, grid 256.
// Raw X staged 2 tiles ahead in 16 INDIVIDUALLY-NAMED f32x4 registers (no arrays ->
// no scratch). cvt (v_cvt_pk_bf16_f32) + 4x ds_write_b128 in q3 under the MFMA
// setprio region. A: 2 LDS buffers (parity); B: gld16 2-buf as in round 5.
// LDS 96 KiB: A 2x32K @0, B 2x16K @65536.
__global__ __launch_bounds__(512, 2)
void gemm1_fused(const float* __restrict__ X, const u16* __restrict__ B,
                 u16* __restrict__ H, int N, int K) {
    const int NT = K >> 6;                  // 128
    __shared__ __align__(1024) char lds[98304];
    const int BOFF = 65536;

    const int tid  = threadIdx.x;
    const int lane = tid & 63;
    const int wave = tid >> 6;
    const int wm   = wave >> 2;
    const int wn   = wave & 3;

    const int nwg = gridDim.x;
    const int swz = (blockIdx.x & 7) * (nwg >> 3) + (blockIdx.x >> 3);
    const int ntn = N >> 7;                 // 8
    const int tm0 = (swz / ntn) << 8;
    const int tn0 = (swz % ntn) << 7;

    const int srl = lane >> 2;
    const int sch = (lane & 3) ^ (((lane >> 5) & 1) << 1);
    const int scol  = (wave & 1) * 32 + sch * 8;    // pre-swizzled element col
    const int srow0 = (wave >> 1) * 16 + srl;

    // fp32 A sources (same rows/cols the bf16 gld16 path used)
    const float* const px00 = X + (size_t)(tm0 + srow0)            * K + scol;
    const float* const px01 = X + (size_t)(tm0 + srow0 + 64)       * K + scol;
    const float* const px10 = X + (size_t)(tm0 + 128 + srow0)      * K + scol;
    const float* const px11 = X + (size_t)(tm0 + 128 + srow0 + 64) * K + scol;
    const u16* const pb0 = B + (size_t)(tn0 + srow0)      * K + scol;
    const u16* const pb1 = B + (size_t)(tn0 + srow0 + 64) * K + scol;

    char* const awr = lds + wave * 1024 + lane * 16;   // this thread's A slot (buf 0)

    // 16 named raw-staging registers — NEVER placed in an array (rule #20)
    f32x4 rE0, rE1, rE2, rE3, rE4, rE5, rE6, rE7;   // even taus
    f32x4 rO0, rO1, rO2, rO3, rO4, rO5, rO6, rO7;   // odd taus

#define LOADR(tau, a0,a1,a2,a3,a4,a5,a6,a7) do {                      \
        size_t _o = (size_t)(tau) * 64;                               \
        a0 = *(const f32x4*)(px00 + _o); a1 = *(const f32x4*)(px00 + _o + 4); \
        a2 = *(const f32x4*)(px01 + _o); a3 = *(const f32x4*)(px01 + _o + 4); \
        a4 = *(const f32x4*)(px10 + _o); a5 = *(const f32x4*)(px10 + _o + 4); \
        a6 = *(const f32x4*)(px11 + _o); a7 = *(const f32x4*)(px11 + _o + 4); \
    } while (0)

#define WRA(bufbit, a0,a1,a2,a3,a4,a5,a6,a7) do {                     \
        uint4 _w;                                                     \
        _w.x = cvtpk(a0[0],a0[1]); _w.y = cvtpk(a0[2],a0[3]);         \
        _w.z = cvtpk(a1[0],a1[1]); _w.w = cvtpk(a1[2],a1[3]);         \
        *(uint4*)(awr + (bufbit) * 32768 +     0 +    0) = _w;        \
        _w.x = cvtpk(a2[0],a2[1]); _w.y = cvtpk(a2[2],a2[3]);         \
        _w.z = cvtpk(a3[0],a3[1]); _w.w = cvtpk(a3[2],a3[3]);         \
        *(uint4*)(awr + (bufbit) * 32768 +     0 + 8192) = _w;        \
        _w.x = cvtpk(a4[0],a4[1]); _w.y = cvtpk(a4[2],a4[3]);         \
        _w.z = cvtpk(a5[0],a5[1]); _w.w = cvtpk(a5[2],a5[3]);         \
        *(uint4*)(awr + (bufbit) * 32768 + 16384 +    0) = _w;        \
        _w.x = cvtpk(a6[0],a6[1]); _w.y = cvtpk(a6[2],a6[3]);         \
        _w.z = cvtpk(a7[0],a7[1]); _w.w = cvtpk(a7[2],a7[3]);         \
        *(uint4*)(awr + (bufbit) * 32768 + 16384 + 8192) = _w;        \
    } while (0)

#define STB(tau) do {                                                 \
        char* _d = lds + BOFF + ((tau) & 1) * 16384 + wave * 1024;    \
        gld16(pb0 + (size_t)(tau) * 64, _d);                          \
        gld16(pb1 + (size_t)(tau) * 64, _d + 8192);                   \
    } while (0)

    const int l15 = lane & 15, lhi = lane >> 4;
    const int pch = lhi ^ (((lane >> 3) & 1) << 1);
    const int lof = l15 * 64 + pch * 16;

    short8 a[4][2];
    short8 b[2][2];
    f32x4  acc[8][2] = {};

    auto MMA_ = [&](int mh, int nh) {
#pragma unroll
        for (int ks = 0; ks < 2; ++ks)
#pragma unroll
            for (int fm = 0; fm < 4; ++fm)
                acc[mh * 4 + fm][nh] = __builtin_amdgcn_mfma_f32_16x16x32_bf16(
                    a[fm][ks], b[nh][ks], acc[mh * 4 + fm][nh], 0, 0, 0);
    };

// one tile; PAR is a literal 0/1; LOADs go to one named set, WRITEs come from the other
#define TILE(T, PAR, LR0,LR1,LR2,LR3,LR4,LR5,LR6,LR7, WR0,WR1,WR2,WR3,WR4,WR5,WR6,WR7) do { \
        const char* Ab = lds + (PAR) * 32768 + wm * 16384 + lof;      \
        const char* Bb = lds + BOFF + (PAR) * 16384 + wn * 4096 + lof;\
        /* q0: issue raw X(T+2); read A[mh0]+B[nh0] */                \
        if ((T) + 2 < NT) LOADR((T) + 2, LR0,LR1,LR2,LR3,LR4,LR5,LR6,LR7); \
        _Pragma("unroll")                                             \
        for (int fm = 0; fm < 4; ++fm)                                \
            _Pragma("unroll")                                         \
            for (int ks = 0; ks < 2; ++ks)                            \
                a[fm][ks] = *(const short8*)(Ab + (fm * 2 + ks) * 1024); \
        _Pragma("unroll")                                             \
        for (int ks = 0; ks < 2; ++ks)                                \
            b[0][ks] = *(const short8*)(Bb + ks * 1024);              \
        SYNC_IN();                                                    \
        __builtin_amdgcn_s_setprio(1);                                \
        MMA_(0, 0);                                                   \
        SYNC_OUT();                                                   \
        /* q1 */                                                      \
        _Pragma("unroll")                                             \
        for (int ks = 0; ks < 2; ++ks)                                \
            b[1][ks] = *(const short8*)(Bb + (2 + ks) * 1024);        \
        SYNC_IN();                                                    \
        __builtin_amdgcn_s_setprio(1);                                \
        MMA_(0, 1);                                                   \
        SYNC_OUT();                                                   \
        /* q2: read A[mh1]; stage B(T+2) */                           \
        _Pragma("unroll")                                             \
        for (int fm = 0; fm < 4; ++fm)                                \
            _Pragma("unroll")                                         \
            for (int ks = 0; ks < 2; ++ks)                            \
                a[fm][ks] = *(const short8*)(Ab + ((4 + fm) * 2 + ks) * 1024); \
        if ((T) + 2 < NT) STB((T) + 2);                               \
        SYNC_IN();                                                    \
        __builtin_amdgcn_s_setprio(1);                                \
        MMA_(1, 1);                                                   \
        SYNC_OUT();                                                   \
        /* q3: drain raw(T+1)+B(T+1); cvt+write A(T+1) under MFMA */  \
        __builtin_amdgcn_s_barrier();                                 \
        if ((T) < NT - 2) asm volatile("s_waitcnt vmcnt(10)" ::: "memory"); \
        else              asm volatile("s_waitcnt vmcnt(0)"  ::: "memory"); \
        __builtin_amdgcn_s_setprio(1);                                \
        if ((T) + 1 < NT) WRA(((T) + 1) & 1, WR0,WR1,WR2,WR3,WR4,WR5,WR6,WR7); \
        MMA_(1, 0);                                                   \
        __builtin_amdgcn_s_setprio(0);                                \
        asm volatile("s_waitcnt lgkmcnt(0)" ::: "memory");            \
        __builtin_amdgcn_s_barrier();                                 \
    } while (0)

    // prologue: raw(0)->E, B(0), raw(1)->O, B(1); drain raw(0)+B(0); write A(0)
    LOADR(0, rE0,rE1,rE2,rE3,rE4,rE5,rE6,rE7);
    STB(0);
    LOADR(1, rO0,rO1,rO2,rO3,rO4,rO5,rO6,rO7);
    STB(1);
    asm volatile("s_waitcnt vmcnt(10)" ::: "memory");
    WRA(0, rE0,rE1,rE2,rE3,rE4,rE5,rE6,rE7);
    asm volatile("s_waitcnt lgkmcnt(0)" ::: "memory");
    __builtin_amdgcn_s_barrier();

    for (int t = 0; t < NT; t += 2) {
        // even tile: load raw(t+2) -> E, write A(t+1) from O (into buf 1)
        TILE(t, 0, rE0,rE1,rE2,rE3,rE4,rE5,rE6,rE7,
                   rO0,rO1,rO2,rO3,rO4,rO5,rO6,rO7);
        // odd tile: load raw(t+3) -> O, write A(t+2) from E (into buf 0)
        TILE(t + 1, 1, rO0,rO1,rO2,rO3,rO4,rO5,rO6,rO7,
                       rE0,rE1,rE2,rE3,rE4,rE5,rE6,rE7);
    }

    // epilogue: bf16 tile via LDS transpose, coalesced 16B stores
    u16* lu = (u16*)lds;
#pragma unroll
    for (int fm = 0; fm < 8; ++fm)
#pragma unroll
        for (int nh = 0; nh < 2; ++nh) {
            const int col  = wn * 32 + nh * 16 + l15;
            const int row0 = wm * 128 + fm * 16 + lhi * 4;
#pragma unroll
            for (int r = 0; r < 4; ++r)
                lu[(row0 + r) * 128 + col] = f2b(acc[fm][nh][r]);
        }
    __syncthreads();
    const uint4* ls = (const uint4*)lds;
#pragma unroll
    for (int s = 0; s < 8; ++s) {
        int i = s * 512 + tid;
        int row = i >> 4;
        int col = (i & 15) * 8;
        *(uint4*)(H + (size_t)(tm0 + row) * N + (tn0 + col)) = ls[i];
    }
#undef TILE
#undef LOADR
#undef WRA
#undef STB
}

// ---------------- GEMM 2: PERSISTENT 1024x256 column-panel blocks (round-9 best) ----------
__global__ __launch_bounds__(512, 2)
void gemm2_persist(const u16* __restrict__ A, const u16* __restrict__ B,
                   float* __restrict__ O, const float* __restrict__ bias,
                   int N, int K) {
    __shared__ __align__(1024) char lds[163840];
    const int BOFF = 98304;
    const int TTOT = 64;

    const int tid  = threadIdx.x;
    const int lane = tid & 63;
    const int wave = tid >> 6;
    const int wm   = wave >> 2;
    const int wn   = wave & 3;

    const int bid = blockIdx.x;
    const int xcd = bid & 7;
    const int sub = (bid >> 3) & 3;
    const int mg  = bid >> 5;
    const int tn0     = ((xcd << 2) + sub) << 8;
    const int tm_base = mg << 10;

    const int srl = lane >> 2;
    const int sch = (lane & 3) ^ (((lane >> 5) & 1) << 1);
    const int scol  = (wave & 1) * 32 + sch * 8;
    const int srow0 = (wave >> 1) * 16 + srl;

    auto STAGE_A = [&](int tau, int half) {
        if (tau < TTOT) {
            char* d = lds + (tau % 3) * 32768 + half * 16384 + wave * 1024;
            const int rb = tm_base + ((tau >> 4) << 8) + half * 128 + srow0;
            const u16* p = A + (size_t)rb * K + ((tau & 15) << 6) + scol;
            gld16(p, d);
            gld16(p + (size_t)64 * K, d + 8192);
        }
    };
    auto STAGE_B = [&](int tau, int half) {
        if (tau < TTOT) {
            char* d = lds + BOFF + (tau & 1) * 32768 + half * 16384 + wave * 1024;
            const u16* p = B + (size_t)(tn0 + half * 128 + srow0) * K + ((tau & 15) << 6) + scol;
            gld16(p, d);
            gld16(p + (size_t)64 * K, d + 8192);
        }
    };

    const int l15 = lane & 15, lhi = lane >> 4;
    const int pch = lhi ^ (((lane >> 3) & 1) << 1);
    const int lof = l15 * 64 + pch * 16;

    short8 a[4][2];
    short8 b[4][2];
    f32x4  acc[8][4] = {};

    const char* Ab;
    const char* Bb;
    auto LDA_ = [&](int mh) {
#pragma unroll
        for (int fm = 0; fm < 4; ++fm)
#pragma unroll
            for (int ks = 0; ks < 2; ++ks)
                a[fm][ks] = *(const short8*)(Ab + ((mh * 4 + fm) * 2 + ks) * 1024);
    };
    auto LDB_ = [&](int nh) {
#pragma unroll
        for (int fn = 0; fn < 2; ++fn)
#pragma unroll
            for (int ks = 0; ks < 2; ++ks)
                b[nh * 2 + fn][ks] = *(const short8*)(Bb + (((wn & 1) * 4 + nh * 2 + fn) * 2 + ks) * 1024);
    };
    auto MMA_ = [&](int mh, int nh) {
#pragma unroll
        for (int ks = 0; ks < 2; ++ks)
#pragma unroll
            for (int fm = 0; fm < 4; ++fm)
#pragma unroll
                for (int fn = 0; fn < 2; ++fn)
                    acc[mh * 4 + fm][nh * 2 + fn] = __builtin_amdgcn_mfma_f32_16x16x32_bf16(
                        a[fm][ks], b[nh * 2 + fn][ks], acc[mh * 4 + fm][nh * 2 + fn], 0, 0, 0);
    };

    const int ocol = tn0 + wn * 64;
    float bv[4];
#pragma unroll
    for (int fn = 0; fn < 4; ++fn) bv[fn] = bias[ocol + fn * 16 + l15];

    STAGE_A(0, 0); STAGE_A(0, 1); STAGE_B(0, 0); STAGE_B(0, 1);
    STAGE_A(1, 0); STAGE_A(1, 1); STAGE_B(1, 0); STAGE_B(1, 1);
    asm volatile("s_waitcnt vmcnt(8)" ::: "memory");
    __builtin_amdgcn_s_barrier();

    for (int tt = 0; tt < TTOT; ++tt) {
        Ab = lds + (tt % 3) * 32768 + wm * 16384 + lof;
        Bb = lds + BOFF + (tt & 1) * 32768 + (wn >> 1) * 16384 + lof;

        LDA_(0); LDB_(0);
        STAGE_A(tt + 2, 0);
        asm volatile("s_waitcnt lgkmcnt(8)" ::: "memory");
        SYNC_IN();
        __builtin_amdgcn_s_setprio(1);
        MMA_(0, 0);
        SYNC_OUT();

        LDB_(1);
        STAGE_A(tt + 2, 1);
        SYNC_IN();
        __builtin_amdgcn_s_setprio(1);
        MMA_(0, 1);
        SYNC_OUT();

        LDA_(1);
        STAGE_B(tt + 2, 0);
        SYNC_IN();
        __builtin_amdgcn_s_setprio(1);
        MMA_(1, 1);
        SYNC_OUT();

        STAGE_B(tt + 2, 1);
        __builtin_amdgcn_s_barrier();
        asm volatile("s_waitcnt lgkmcnt(0)" ::: "memory");
        __builtin_amdgcn_s_setprio(1);
        MMA_(1, 0);
        __builtin_amdgcn_s_setprio(0);
        if (tt < TTOT - 2)       asm volatile("s_waitcnt vmcnt(8)" ::: "memory");
        else if (tt == TTOT - 2) asm volatile("s_waitcnt vmcnt(0)" ::: "memory");
        __builtin_amdgcn_s_barrier();

        if ((tt & 15) == 15) {
            const int orow = tm_base + ((tt >> 4) << 8) + wm * 128;
#pragma unroll
            for (int fm = 0; fm < 8; ++fm) {
                const int row0 = orow + fm * 16 + lhi * 4;
#pragma unroll
                for (int fn = 0; fn < 4; ++fn) {
                    const int col = ocol + fn * 16 + l15;
#pragma unroll
                    for (int r = 0; r < 4; ++r) {
                        float v = acc[fm][fn][r] + bv[fn];
                        O[(size_t)(row0 + r) * N + col] = v > 0.f ? v : 0.f;
                        acc[fm][fn][r] = 0.f;
                    }
                }
            }
        }
    }
}

// ---------------- launch ----------------

extern "C" void kernel_launch(void* const* d_in, const int* in_sizes, int n_in,
                              void* d_out, int out_size, void* d_ws, size_t ws_size,
                              hipStream_t stream) {
    const float* x    = (const float*)d_in[0];   // [8192, 8192]
    const float* W    = (const float*)d_in[1];   // [8192, 1024]
    const float* bias = (const float*)d_in[2];   // [8192]
    float* out = (float*)d_out;                  // [8192, 8192] fp32

    char* ws = (char*)d_ws;
    u16* wt = (u16*)ws;                          // [1024][8192]  16 MB
    u16* wb = (u16*)(ws + 16777216);             // [8192][1024]  16 MB
    u16* hb = (u16*)(ws + 2 * 16777216);         // [8192][1024]  16 MB

    cvt_w_kernel<<<dim3(NFEAT / 64, DMODEL / 64), 256, 0, stream>>>(W, wb, wt);

    // h = bf16(x) @ W -> bf16 (x converted in-flight via named-reg staging)
    gemm1_fused<<<dim3((BATCH / 256) * (DMODEL / 128)), 512, 0, stream>>>(
        x, wt, hb, DMODEL, NFEAT);

    // out = relu(h @ W^T + bias)
    gemm2_persist<<<dim3(256), 512, 0, stream>>>(
        hb, wb, out, bias, NFEAT, DMODEL);
}

// Round 12
// 373.085 us; speedup vs baseline: 1.2444x; 1.0815x over previous
//
#include <hip/hip_runtime.h>
#include <hip/hip_bf16.h>
#include <stdint.h>

#define BATCH  8192
#define NFEAT  8192
#define DMODEL 1024

typedef unsigned short u16;
typedef __attribute__((ext_vector_type(8))) short  short8;
typedef __attribute__((ext_vector_type(4))) float  f32x4;

// fp32 -> bf16 round-to-nearest-even
__device__ __forceinline__ u16 f2b(float f) {
    uint32_t u = __float_as_uint(f);
    u += 0x7fffu + ((u >> 16) & 1u);
    return (u16)(u >> 16);
}

// async global->LDS, 16B per lane; LDS dest is wave-uniform base + lane*16 (HW rule)
__device__ __forceinline__ void gld16(const u16* g, void* l) {
    __builtin_amdgcn_global_load_lds(
        (const __attribute__((address_space(1))) void*)(uintptr_t)g,
        (__attribute__((address_space(3))) void*)(uint32_t)(uintptr_t)l,
        16, 0, 0);
}

// ---------------- conversion kernels ----------------

__global__ void cvt_x_kernel(const float* __restrict__ x, u16* __restrict__ xb) {
    int i = blockIdx.x * blockDim.x + threadIdx.x;
    const float4* xv = (const float4*)x;
    float4 a = xv[2 * i];
    float4 b = xv[2 * i + 1];
    union { u16 u[8]; uint4 v; } o;
    o.u[0] = f2b(a.x); o.u[1] = f2b(a.y); o.u[2] = f2b(a.z); o.u[3] = f2b(a.w);
    o.u[4] = f2b(b.x); o.u[5] = f2b(b.y); o.u[6] = f2b(b.z); o.u[7] = f2b(b.w);
    ((uint4*)xb)[i] = o.v;
}

__global__ void cvt_w_kernel(const float* __restrict__ W,
                             u16* __restrict__ wb, u16* __restrict__ wt) {
    __shared__ u16 tile[64][65];
    const int f0 = blockIdx.x * 64;
    const int d0 = blockIdx.y * 64;
    const int t  = threadIdx.x;
#pragma unroll
    for (int rep = 0; rep < 16; ++rep) {
        int idx = rep * 256 + t;
        int r = idx >> 6, c = idx & 63;
        float v = W[(size_t)(f0 + r) * DMODEL + d0 + c];
        u16 u = f2b(v);
        tile[r][c] = u;
        wb[(size_t)(f0 + r) * DMODEL + d0 + c] = u;
    }
    __syncthreads();
#pragma unroll
    for (int rep = 0; rep < 16; ++rep) {
        int idx = rep * 256 + t;
        int r = idx >> 6, c = idx & 63;
        wt[(size_t)(d0 + r) * NFEAT + f0 + c] = tile[c][r];
    }
}

#define SYNC_IN()  do { __builtin_amdgcn_s_barrier(); \
                        asm volatile("s_waitcnt lgkmcnt(0)" ::: "memory"); } while (0)
#define SYNC_OUT() do { __builtin_amdgcn_s_setprio(0); __builtin_amdgcn_s_barrier(); } while (0)

// ---------------- GEMM 1: 256x128 tile, 2 phases/K-tile (4 barriers), A 3-buf --------------
// H = A @ B^T (bf16 out). A [M][K], B [N][K]. Grid 256. LDS 128 KiB: A 3x32K, B 2x16K @98304.
// ph0: read A[mh0]+B(all), stage A(t+2) both halves, 16 MFMA.
// ph1: read A[mh1], stage B(t+2), 16 MFMA, counted vmcnt(6).
__global__ __launch_bounds__(512, 2)
void gemm1_2ph(const u16* __restrict__ A, const u16* __restrict__ B,
               u16* __restrict__ H, int N, int K) {
    const int NT = K >> 6;
    __shared__ __align__(1024) char lds[131072];
    const int BOFF = 98304;

    const int tid  = threadIdx.x;
    const int lane = tid & 63;
    const int wave = tid >> 6;
    const int wm   = wave >> 2;
    const int wn   = wave & 3;

    const int nwg = gridDim.x;
    const int swz = (blockIdx.x & 7) * (nwg >> 3) + (blockIdx.x >> 3);
    const int ntn = N >> 7;
    const int tm0 = (swz / ntn) << 8;
    const int tn0 = (swz % ntn) << 7;

    const int srl = lane >> 2;
    const int sch = (lane & 3) ^ (((lane >> 5) & 1) << 1);
    const int scol  = (wave & 1) * 32 + sch * 8;
    const int srow0 = (wave >> 1) * 16 + srl;

    const u16* pa[2][2];
    pa[0][0] = A + (size_t)(tm0 + srow0)            * K + scol;
    pa[0][1] = A + (size_t)(tm0 + srow0 + 64)       * K + scol;
    pa[1][0] = A + (size_t)(tm0 + 128 + srow0)      * K + scol;
    pa[1][1] = A + (size_t)(tm0 + 128 + srow0 + 64) * K + scol;
    const u16* pb[2];
    pb[0] = B + (size_t)(tn0 + srow0)      * K + scol;
    pb[1] = B + (size_t)(tn0 + srow0 + 64) * K + scol;

    auto STAGE_A = [&](int tau, int half) {
        if (tau < NT) {
            char* d = lds + (tau % 3) * 32768 + half * 16384 + wave * 1024;
            gld16(pa[half][0] + (size_t)tau * 64, d);
            gld16(pa[half][1] + (size_t)tau * 64, d + 8192);
        }
    };
    auto STAGE_B = [&](int tau) {
        if (tau < NT) {
            char* d = lds + BOFF + (tau & 1) * 16384 + wave * 1024;
            gld16(pb[0] + (size_t)tau * 64, d);
            gld16(pb[1] + (size_t)tau * 64, d + 8192);
        }
    };

    const int l15 = lane & 15, lhi = lane >> 4;
    const int pch = lhi ^ (((lane >> 3) & 1) << 1);
    const int lof = l15 * 64 + pch * 16;

    short8 a[4][2];
    short8 b[2][2];
    f32x4  acc[8][2] = {};

    const char* Ab;
    const char* Bb;
    auto LDA_ = [&](int mh) {
#pragma unroll
        for (int fm = 0; fm < 4; ++fm)
#pragma unroll
            for (int ks = 0; ks < 2; ++ks)
                a[fm][ks] = *(const short8*)(Ab + ((mh * 4 + fm) * 2 + ks) * 1024);
    };
    auto LDB_ = [&](int nh) {
#pragma unroll
        for (int ks = 0; ks < 2; ++ks)
            b[nh][ks] = *(const short8*)(Bb + (nh * 2 + ks) * 1024);
    };
    auto MMA_ = [&](int mh, int nh) {
#pragma unroll
        for (int ks = 0; ks < 2; ++ks)
#pragma unroll
            for (int fm = 0; fm < 4; ++fm)
                acc[mh * 4 + fm][nh] = __builtin_amdgcn_mfma_f32_16x16x32_bf16(
                    a[fm][ks], b[nh][ks], acc[mh * 4 + fm][nh], 0, 0, 0);
    };

    STAGE_A(0, 0); STAGE_A(0, 1); STAGE_B(0);
    STAGE_A(1, 0); STAGE_A(1, 1); STAGE_B(1);
    asm volatile("s_waitcnt vmcnt(6)" ::: "memory");
    __builtin_amdgcn_s_barrier();

    for (int t = 0; t < NT; ++t) {
        Ab = lds + (t % 3) * 32768 + wm * 16384 + lof;
        Bb = lds + BOFF + (t & 1) * 16384 + wn * 4096 + lof;

        // ph0: A[mh0](8) + B all(4); stage A(t+2) h0,h1; 16 MFMA
        LDA_(0); LDB_(0); LDB_(1);
        STAGE_A(t + 2, 0);
        STAGE_A(t + 2, 1);
        SYNC_IN();
        __builtin_amdgcn_s_setprio(1);
        MMA_(0, 0);
        MMA_(0, 1);
        SYNC_OUT();

        // ph1: A[mh1](8); stage B(t+2); 16 MFMA; counted drain
        LDA_(1);
        STAGE_B(t + 2);
        SYNC_IN();
        __builtin_amdgcn_s_setprio(1);
        MMA_(1, 1);
        MMA_(1, 0);
        __builtin_amdgcn_s_setprio(0);
        // queue: [A(t+1)4,B(t+1)2, A(t+2)4,B(t+2)2] -> drain (t+1)'s 6
        if (t < NT - 2)       asm volatile("s_waitcnt vmcnt(6)" ::: "memory");
        else if (t == NT - 2) asm volatile("s_waitcnt vmcnt(0)" ::: "memory");
        __builtin_amdgcn_s_barrier();
    }

    // epilogue: bf16 tile via LDS transpose, coalesced 16B stores
    u16* lu = (u16*)lds;
#pragma unroll
    for (int fm = 0; fm < 8; ++fm)
#pragma unroll
        for (int nh = 0; nh < 2; ++nh) {
            const int col  = wn * 32 + nh * 16 + l15;
            const int row0 = wm * 128 + fm * 16 + lhi * 4;
#pragma unroll
            for (int r = 0; r < 4; ++r)
                lu[(row0 + r) * 128 + col] = f2b(acc[fm][nh][r]);
        }
    __syncthreads();
    const uint4* ls = (const uint4*)lds;
#pragma unroll
    for (int s = 0; s < 8; ++s) {
        int i = s * 512 + tid;
        int row = i >> 4;
        int col = (i & 15) * 8;
        *(uint4*)(H + (size_t)(tm0 + row) * N + (tn0 + col)) = ls[i];
    }
}

// ---------------- GEMM 2: persistent 1024x256 panels, 2 phases/K-tile (4 barriers) --------
// out = relu(A @ B^T + bias), fp32. Grid 256 (1/CU), 4 chained 256x256 tiles/block,
// continuous tau pipeline. LDS 160 KiB: A 3x32K @0, B 2x32K @98304.
__global__ __launch_bounds__(512, 2)
void gemm2_persist(const u16* __restrict__ A, const u16* __restrict__ B,
                   float* __restrict__ O, const float* __restrict__ bias,
                   int N, int K) {
    __shared__ __align__(1024) char lds[163840];
    const int BOFF = 98304;
    const int TTOT = 64;

    const int tid  = threadIdx.x;
    const int lane = tid & 63;
    const int wave = tid >> 6;
    const int wm   = wave >> 2;
    const int wn   = wave & 3;

    const int bid = blockIdx.x;
    const int xcd = bid & 7;
    const int sub = (bid >> 3) & 3;
    const int mg  = bid >> 5;
    const int tn0     = ((xcd << 2) + sub) << 8;
    const int tm_base = mg << 10;

    const int srl = lane >> 2;
    const int sch = (lane & 3) ^ (((lane >> 5) & 1) << 1);
    const int scol  = (wave & 1) * 32 + sch * 8;
    const int srow0 = (wave >> 1) * 16 + srl;

    auto STAGE_A = [&](int tau, int half) {
        if (tau < TTOT) {
            char* d = lds + (tau % 3) * 32768 + half * 16384 + wave * 1024;
            const int rb = tm_base + ((tau >> 4) << 8) + half * 128 + srow0;
            const u16* p = A + (size_t)rb * K + ((tau & 15) << 6) + scol;
            gld16(p, d);
            gld16(p + (size_t)64 * K, d + 8192);
        }
    };
    auto STAGE_B = [&](int tau, int half) {
        if (tau < TTOT) {
            char* d = lds + BOFF + (tau & 1) * 32768 + half * 16384 + wave * 1024;
            const u16* p = B + (size_t)(tn0 + half * 128 + srow0) * K + ((tau & 15) << 6) + scol;
            gld16(p, d);
            gld16(p + (size_t)64 * K, d + 8192);
        }
    };

    const int l15 = lane & 15, lhi = lane >> 4;
    const int pch = lhi ^ (((lane >> 3) & 1) << 1);
    const int lof = l15 * 64 + pch * 16;

    short8 a[4][2];
    short8 b[4][2];
    f32x4  acc[8][4] = {};

    const char* Ab;
    const char* Bb;
    auto LDA_ = [&](int mh) {
#pragma unroll
        for (int fm = 0; fm < 4; ++fm)
#pragma unroll
            for (int ks = 0; ks < 2; ++ks)
                a[fm][ks] = *(const short8*)(Ab + ((mh * 4 + fm) * 2 + ks) * 1024);
    };
    auto LDB_ = [&](int nh) {
#pragma unroll
        for (int fn = 0; fn < 2; ++fn)
#pragma unroll
            for (int ks = 0; ks < 2; ++ks)
                b[nh * 2 + fn][ks] = *(const short8*)(Bb + (((wn & 1) * 4 + nh * 2 + fn) * 2 + ks) * 1024);
    };
    auto MMA_ = [&](int mh, int nh) {
#pragma unroll
        for (int ks = 0; ks < 2; ++ks)
#pragma unroll
            for (int fm = 0; fm < 4; ++fm)
#pragma unroll
                for (int fn = 0; fn < 2; ++fn)
                    acc[mh * 4 + fm][nh * 2 + fn] = __builtin_amdgcn_mfma_f32_16x16x32_bf16(
                        a[fm][ks], b[nh * 2 + fn][ks], acc[mh * 4 + fm][nh * 2 + fn], 0, 0, 0);
    };

    const int ocol = tn0 + wn * 64;
    float bv[4];
#pragma unroll
    for (int fn = 0; fn < 4; ++fn) bv[fn] = bias[ocol + fn * 16 + l15];

    STAGE_A(0, 0); STAGE_A(0, 1); STAGE_B(0, 0); STAGE_B(0, 1);
    STAGE_A(1, 0); STAGE_A(1, 1); STAGE_B(1, 0); STAGE_B(1, 1);
    asm volatile("s_waitcnt vmcnt(8)" ::: "memory");
    __builtin_amdgcn_s_barrier();

    for (int tt = 0; tt < TTOT; ++tt) {
        Ab = lds + (tt % 3) * 32768 + wm * 16384 + lof;
        Bb = lds + BOFF + (tt & 1) * 32768 + (wn >> 1) * 16384 + lof;

        // ph0: A[mh0](8) + B all(8); stage A(tt+2) h0,h1; 32 MFMA
        LDA_(0); LDB_(0); LDB_(1);
        STAGE_A(tt + 2, 0);
        STAGE_A(tt + 2, 1);
        SYNC_IN();
        __builtin_amdgcn_s_setprio(1);
        MMA_(0, 0);
        MMA_(0, 1);
        SYNC_OUT();

        // ph1: A[mh1](8); stage B(tt+2) h0,h1; 32 MFMA; counted drain
        LDA_(1);
        STAGE_B(tt + 2, 0);
        STAGE_B(tt + 2, 1);
        SYNC_IN();
        __builtin_amdgcn_s_setprio(1);
        MMA_(1, 1);
        MMA_(1, 0);
        __builtin_amdgcn_s_setprio(0);
        // queue: [A(tt+1)4,B(tt+1)4, A(tt+2)4,B(tt+2)4] -> drain (tt+1)'s 8
        if (tt < TTOT - 2)       asm volatile("s_waitcnt vmcnt(8)" ::: "memory");
        else if (tt == TTOT - 2) asm volatile("s_waitcnt vmcnt(0)" ::: "memory");
        __builtin_amdgcn_s_barrier();

        // per-tile epilogue after the barrier: stores overlap next tile's K-loop
        if ((tt & 15) == 15) {
            const int orow = tm_base + ((tt >> 4) << 8) + wm * 128;
#pragma unroll
            for (int fm = 0; fm < 8; ++fm) {
                const int row0 = orow + fm * 16 + lhi * 4;
#pragma unroll
                for (int fn = 0; fn < 4; ++fn) {
                    const int col = ocol + fn * 16 + l15;
#pragma unroll
                    for (int r = 0; r < 4; ++r) {
                        float v = acc[fm][fn][r] + bv[fn];
                        O[(size_t)(row0 + r) * N + col] = v > 0.f ? v : 0.f;
                        acc[fm][fn][r] = 0.f;
                    }
                }
            }
        }
    }
}

// ---------------- launch ----------------

extern "C" void kernel_launch(void* const* d_in, const int* in_sizes, int n_in,
                              void* d_out, int out_size, void* d_ws, size_t ws_size,
                              hipStream_t stream) {
    const float* x    = (const float*)d_in[0];   // [8192, 8192]
    const float* W    = (const float*)d_in[1];   // [8192, 1024]
    const float* bias = (const float*)d_in[2];   // [8192]
    float* out = (float*)d_out;                  // [8192, 8192] fp32

    char* ws = (char*)d_ws;
    u16* xb = (u16*)ws;                                        // 134217728 B
    u16* wt = (u16*)(ws + 134217728);                          // [1024][8192]
    u16* wb = (u16*)(ws + 134217728 + 16777216);               // [8192][1024]
    u16* hb = (u16*)(ws + 134217728 + 2 * 16777216);           // [8192][1024]

    cvt_x_kernel<<<(BATCH * NFEAT / 8) / 256, 256, 0, stream>>>(x, xb);
    cvt_w_kernel<<<dim3(NFEAT / 64, DMODEL / 64), 256, 0, stream>>>(W, wb, wt);

    gemm1_2ph<<<dim3((BATCH / 256) * (DMODEL / 128)), 512, 0, stream>>>(
        xb, wt, hb, DMODEL, NFEAT);

    gemm2_persist<<<dim3(256), 512, 0, stream>>>(
        hb, wb, out, bias, NFEAT, DMODEL);
}